// Round 1
// baseline (24094.766 us; speedup 1.0000x reference)
//
#include <hip/hip_runtime.h>
#include <cmath>

#define SS 512
#define BB 64
#define II 256
#define HH 1024
#define BH (BB*HH)   // 65536

typedef _Float16 half8 __attribute__((ext_vector_type(8)));
typedef float    floatx4 __attribute__((ext_vector_type(4)));

// ---------------------------------------------------------------------------
// prep_misc: convert X fp32->fp16, zero h buffer 0 (hi+lo), zero flags/epoch
// grid 4096 x 256 = 1,048,576 threads
// ---------------------------------------------------------------------------
__global__ void prep_misc(const float* __restrict__ X, _Float16* __restrict__ X16,
                          _Float16* __restrict__ h_hi, _Float16* __restrict__ h_lo,
                          unsigned* __restrict__ flags) {
    const int tid = blockIdx.x * 256 + threadIdx.x;
    const size_t base = (size_t)tid * 8;   // 8 elems/thread covers 8,388,608 exactly
    #pragma unroll
    for (int j = 0; j < 8; ++j) X16[base + j] = (_Float16)X[base + j];
    // zero h buf0: 3*64*1024 halfs = 393,216 B each array -> 49,152 x 8B
    if (tid < 49152) {
        ((unsigned long long*)h_hi)[tid] = 0ULL;
        ((unsigned long long*)h_lo)[tid] = 0ULL;
    }
    if (tid < 256) flags[tid] = 0u;   // flags[0..191]; [192] unused now
}

// ---------------------------------------------------------------------------
// prep_bpack: pack per-WG weight slices into MFMA B-fragment order, fp16.
// WG w = (layer = w>>6) x (n-group g = w&63, 16 cols), full K.
// Frag f = k-step (32 K per frag). Layer0: f 0..7 = Wxh, 8..39 = Whh (40 frags).
// Layer l>=1: f 0..31 = U_{l-1}, 32..63 = W_{l-1} (64 frags).
// Frag layout (16x16x32 f16 B operand): lane holds B[k=(lane>>4)*8+j][n=lane&15].
// One thread per (w, f, lane): 192*64*64 = 786,432 -> 3072 x 256.
// ---------------------------------------------------------------------------
__global__ void prep_bpack(const float* __restrict__ Wxh, const float* __restrict__ Whh,
                           const float* __restrict__ Wl,  const float* __restrict__ Ul,
                           _Float16* __restrict__ Bpack) {
    const int tid  = blockIdx.x * 256 + threadIdx.x;
    const int w    = tid >> 12;         // workgroup id 0..191
    const int r    = tid & 4095;
    const int f    = r >> 6;            // frag 0..63
    const int lane = r & 63;
    const int layer = w >> 6;
    const int g     = w & 63;
    const int n  = g * 16 + (lane & 15);
    const int kq = (lane >> 4) * 8;
    const float* src;
    int k;
    if (layer == 0) {
        if (f >= 40) return;            // layer0: 8 X-frags + 32 Whh-frags
        if (f < 8) { src = Wxh; k = f * 32 + kq; }
        else       { src = Whh; k = (f - 8) * 32 + kq; }
    } else {
        const int li = layer - 1;
        if (f < 32) { src = Ul + (size_t)li * HH * HH; k = f * 32 + kq; }
        else        { src = Wl + (size_t)li * HH * HH; k = (f - 32) * 32 + kq; }
    }
    _Float16* dst = Bpack + (size_t)w * 32768 + (size_t)f * 512 + (size_t)lane * 8;
    #pragma unroll
    for (int j = 0; j < 8; ++j) dst[j] = (_Float16)src[(size_t)(k + j) * HH + n];
}

// ---------------------------------------------------------------------------
// Persistent RNN kernel. 192 WGs x 512 threads (8 waves), all co-resident.
// WG = (layer 0..2) x (n-group 0..63, 16 cols).
// NEW vs previous version:
//  * 8 waves/WG: waves 0-3 (kh=0) take the first half of K, waves 4-7 (kh=1)
//    the second half -> 2 waves/SIMD for latency hiding; partials combined
//    through a small LDS buffer. Same total MFMA count, half the chain/wave.
//  * Flat 2-hop barrier: every WG polls all 192 flags directly (lane i polls
//    flag i) -- removes the WG0-gather + epoch-broadcast hops and one full
//    wbl2/buffer_inv round per step.
//  * Non-temporal stores for h hi/lo and out (written once, never re-read by
//    writer) to shrink the dirty-L2 drain done by the release fence.
// ---------------------------------------------------------------------------
__global__ __launch_bounds__(512, 2) void rnn_persist(
        const _Float16* __restrict__ X16,
        const _Float16* __restrict__ Bpack,
        _Float16* __restrict__ h_hi,   // [2][3][B][H]
        _Float16* __restrict__ h_lo,
        unsigned* __restrict__ flags,  // [192] monotonic step counters
        unsigned* __restrict__ epoch,  // unused (kept for signature)
        const float* __restrict__ b_h,
        const float* __restrict__ b_layers,
        float* __restrict__ out) {
    (void)epoch;

    const int wgid  = blockIdx.x;
    const int layer = wgid >> 6;
    const int g     = wgid & 63;
    const int n0    = g * 16;

    const int tid  = threadIdx.x;
    const int wave = tid >> 6;
    const int lane = tid & 63;
    const int rw   = wave & 3;                  // row-wave 0..3 (16 batch rows each)
    const int kh   = wave >> 2;                 // k-half 0/1
    const int rowm = rw * 16 + (lane & 15);     // batch row 0..63
    const int kq   = (lane >> 4) * 8;

    // ---- stage this WG's weight slice into LDS (frag-packed, <=64 KB) ----
    __shared__ __align__(16) _Float16 Bs[64 * 512];
    __shared__ __align__(16) floatx4  Rbuf[4 * 64];   // cross-wave K-partials
    {
        const int nvec = (layer == 0) ? 40 * 64 : 64 * 64;   // uint4s
        const uint4* src = (const uint4*)(Bpack + (size_t)wgid * 32768);
        uint4* dst = (uint4*)Bs;
        for (int i = tid; i < nvec; i += 512) dst[i] = src[i];
    }
    __syncthreads();

    const float bv = (layer == 0) ? b_h[n0 + (lane & 15)]
                                  : b_layers[(size_t)(layer - 1) * HH + n0 + (lane & 15)];

    for (int t = 0; t < SS; ++t) {
        const int rb = t & 1;
        const _Float16* hi = h_hi + (size_t)rb * 3 * BH;
        const _Float16* lo = h_lo + (size_t)rb * 3 * BH;
        _Float16* nhi = h_hi + (size_t)(rb ^ 1) * 3 * BH;
        _Float16* nlo = h_lo + (size_t)(rb ^ 1) * 3 * BH;

        floatx4 accH = (floatx4){0.f, 0.f, 0.f, 0.f};
        floatx4 accL = (floatx4){0.f, 0.f, 0.f, 0.f};

        // ks0 = first k-step (within segment) for this wave's K-half;
        // fb + ks0 + ks = global frag index in Bs (must match prep_bpack).
        auto do_seg = [&](const _Float16* Ahi, const _Float16* Alo,
                          int astride, int ks0, int nsteps, int fb) {
            const size_t rowoff = (size_t)rowm * astride + kq + (size_t)ks0 * 32;
            #pragma unroll 8
            for (int ks = 0; ks < nsteps; ++ks) {
                const half8 a  = *(const half8*)(Ahi + rowoff + ks * 32);
                const half8 bb = *(const half8*)(&Bs[(fb + ks0 + ks) * 512 + lane * 8]);
                accH = __builtin_amdgcn_mfma_f32_16x16x32_f16(a, bb, accH, 0, 0, 0);
                if (Alo) {
                    const half8 al = *(const half8*)(Alo + rowoff + ks * 32);
                    accL = __builtin_amdgcn_mfma_f32_16x16x32_f16(al, bb, accL, 0, 0, 0);
                }
            }
        };

        if (layer == 0) {
            // X: 8 frags total -> 4 per K-half; Whh: 32 frags -> 16 per K-half.
            do_seg(X16 + (size_t)t * BB * II, nullptr, II, kh * 4, 4, 0);
            do_seg(hi + 0 * BH, lo + 0 * BH, HH, kh * 16, 16, 8);
        } else if (layer == 1) {
            do_seg(hi + 1 * BH, lo + 1 * BH, HH, kh * 16, 16, 0);
            do_seg(hi + 0 * BH, lo + 0 * BH, HH, kh * 16, 16, 32);
        } else {
            do_seg(hi + 2 * BH, lo + 2 * BH, HH, kh * 16, 16, 0);
            do_seg(hi + 1 * BH, lo + 1 * BH, HH, kh * 16, 16, 32);
        }

        floatx4 s = accH + accL;
        if (kh == 1) Rbuf[rw * 64 + lane] = s;
        __syncthreads();

        // ---- waves 0-3 combine K-halves, finalize own 64x16 tile ----
        if (kh == 0) {
            const floatx4 s2 = Rbuf[rw * 64 + lane];
            const int n  = n0 + (lane & 15);
            const int mb = rw * 16 + (lane >> 4) * 4;
            #pragma unroll
            for (int rr = 0; rr < 4; ++rr) {
                const float v = tanhf(s[rr] + s2[rr] + bv);
                const int m = mb + rr;
                const size_t hoff = (size_t)layer * BH + (size_t)m * HH + n;
                const _Float16 vh = (_Float16)v;
                __builtin_nontemporal_store(vh, &nhi[hoff]);
                __builtin_nontemporal_store((_Float16)(v - (float)vh), &nlo[hoff]);
                if (layer == 2)
                    __builtin_nontemporal_store(v, &out[(size_t)t * BH + (size_t)m * HH + n]);
                if (t == SS - 1)
                    __builtin_nontemporal_store(v,
                        &out[(size_t)SS * BH + (size_t)layer * BH + (size_t)m * HH + n]);
            }
        }
        __syncthreads();

        // ---- flat 2-hop device barrier: publish flag, poll all 192 flags ----
        if (tid == 0)
            __hip_atomic_store(&flags[wgid], (unsigned)(t + 1),
                               __ATOMIC_RELEASE, __HIP_MEMORY_SCOPE_AGENT);
        if (tid < 192) {
            while (__hip_atomic_load(&flags[tid], __ATOMIC_RELAXED,
                                     __HIP_MEMORY_SCOPE_AGENT) < (unsigned)(t + 1))
                __builtin_amdgcn_s_sleep(1);
        }
        __syncthreads();
        __builtin_amdgcn_fence(__ATOMIC_ACQUIRE, "agent");
    }
}

// ---------------------------------------------------------------------------
extern "C" void kernel_launch(void* const* d_in, const int* in_sizes, int n_in,
                              void* d_out, int out_size, void* d_ws, size_t ws_size,
                              hipStream_t stream) {
    (void)in_sizes; (void)n_in; (void)out_size; (void)ws_size;
    const float* X   = (const float*)d_in[0];
    const float* Wxh = (const float*)d_in[1];
    const float* Whh = (const float*)d_in[2];
    const float* bh  = (const float*)d_in[3];
    const float* Wl  = (const float*)d_in[4];
    const float* Ul  = (const float*)d_in[5];
    const float* bl  = (const float*)d_in[6];
    float* out = (float*)d_out;

    char* ws = (char*)d_ws;
    _Float16* X16   = (_Float16*)(ws);                                   // 16,777,216 B
    _Float16* Bpack = (_Float16*)(ws + 16777216);                        // 12,582,912 B
    _Float16* h_hi  = (_Float16*)(ws + 16777216 + 12582912);             //    786,432 B
    _Float16* h_lo  = (_Float16*)(ws + 16777216 + 12582912 + 786432);    //    786,432 B
    unsigned* flags = (unsigned*)(ws + 16777216 + 12582912 + 2 * 786432); //    1,024 B

    hipLaunchKernelGGL(prep_misc,  dim3(4096), dim3(256), 0, stream, X, X16, h_hi, h_lo, flags);
    hipLaunchKernelGGL(prep_bpack, dim3(3072), dim3(256), 0, stream, Wxh, Whh, Wl, Ul, Bpack);
    hipLaunchKernelGGL(rnn_persist, dim3(192), dim3(512), 0, stream,
                       X16, Bpack, h_hi, h_lo, flags, flags + 192, bh, bl, out);
}

// Round 2
// 8697.346 us; speedup vs baseline: 2.7704x; 2.7704x over previous
//
#include <hip/hip_runtime.h>
#include <cmath>

#define SS 512
#define BB 64
#define II 256
#define HH 1024
#define BH (BB*HH)   // 65536

typedef _Float16 half8 __attribute__((ext_vector_type(8)));
typedef float    floatx4 __attribute__((ext_vector_type(4)));

// ---------------------------------------------------------------------------
// prep_misc: convert X fp32->fp16, zero h buffer 0 (hi+lo), zero flags/epoch
// ---------------------------------------------------------------------------
__global__ void prep_misc(const float* __restrict__ X, _Float16* __restrict__ X16,
                          _Float16* __restrict__ h_hi, _Float16* __restrict__ h_lo,
                          unsigned* __restrict__ flags) {
    const int tid = blockIdx.x * 256 + threadIdx.x;
    const size_t base = (size_t)tid * 8;   // 8 elems/thread covers 8,388,608 exactly
    #pragma unroll
    for (int j = 0; j < 8; ++j) X16[base + j] = (_Float16)X[base + j];
    if (tid < 49152) {
        ((unsigned long long*)h_hi)[tid] = 0ULL;
        ((unsigned long long*)h_lo)[tid] = 0ULL;
    }
    if (tid < 256) flags[tid] = 0u;   // flags[0..191], epoch at [192]
}

// ---------------------------------------------------------------------------
// prep_bpack: pack per-WG weight slices into MFMA B-fragment order, fp16.
// (identical to round-0 geometry: WG = layer x 16-col n-group, full K)
// ---------------------------------------------------------------------------
__global__ void prep_bpack(const float* __restrict__ Wxh, const float* __restrict__ Whh,
                           const float* __restrict__ Wl,  const float* __restrict__ Ul,
                           _Float16* __restrict__ Bpack) {
    const int tid  = blockIdx.x * 256 + threadIdx.x;
    const int w    = tid >> 12;         // workgroup id 0..191
    const int r    = tid & 4095;
    const int f    = r >> 6;            // frag 0..63
    const int lane = r & 63;
    const int layer = w >> 6;
    const int g     = w & 63;
    const int n  = g * 16 + (lane & 15);
    const int kq = (lane >> 4) * 8;
    const float* src;
    int k;
    if (layer == 0) {
        if (f >= 40) return;            // layer0: 8 X-frags + 32 Whh-frags
        if (f < 8) { src = Wxh; k = f * 32 + kq; }
        else       { src = Whh; k = (f - 8) * 32 + kq; }
    } else {
        const int li = layer - 1;
        if (f < 32) { src = Ul + (size_t)li * HH * HH; k = f * 32 + kq; }
        else        { src = Wl + (size_t)li * HH * HH; k = (f - 32) * 32 + kq; }
    }
    _Float16* dst = Bpack + (size_t)w * 32768 + (size_t)f * 512 + (size_t)lane * 8;
    #pragma unroll
    for (int j = 0; j < 8; ++j) dst[j] = (_Float16)src[(size_t)(k + j) * HH + n];
}

// ---------------------------------------------------------------------------
// Coherence-by-access helpers (agent scope = sc1 on gfx950).
// sc1 loads read at the Infinity-Cache coherence point (never cache stale L2);
// sc1 stores write through (nothing dirty in L2) -> NO buffer_wbl2/buffer_inv
// anywhere in the step loop.
// ---------------------------------------------------------------------------
#define LD16C(dst, base, BYTEOFF) \
    asm volatile("global_load_dwordx4 %0, %1, off offset:%c2 sc1" \
                 : "=&v"(dst) : "v"(base), "n"(BYTEOFF))

#define WAITV(N) do { \
    asm volatile("s_waitcnt vmcnt(%c0)" :: "n"(N) : "memory"); \
    __builtin_amdgcn_sched_barrier(0); } while (0)

#define ST2C(p, u32) \
    asm volatile("global_store_short %0, %1, off sc1" :: "v"(p), "v"(u32) : "memory")

struct B8 { half8 a0, a1, a2, a3, a4, a5, a6, a7; };

#define MFMA16(A, B, C) __builtin_amdgcn_mfma_f32_16x16x32_f16(A, B, C, 0, 0, 0)

#define ISSUE8(BUF, P, K0) do { \
    LD16C(BUF.a0, P, ((K0)+0)*64); LD16C(BUF.a1, P, ((K0)+1)*64); \
    LD16C(BUF.a2, P, ((K0)+2)*64); LD16C(BUF.a3, P, ((K0)+3)*64); \
    LD16C(BUF.a4, P, ((K0)+4)*64); LD16C(BUF.a5, P, ((K0)+5)*64); \
    LD16C(BUF.a6, P, ((K0)+6)*64); LD16C(BUF.a7, P, ((K0)+7)*64); } while (0)

// ---------------------------------------------------------------------------
// Persistent RNN kernel: 192 WGs x 256 threads (round-0 geometry).
// Changes vs round 0: sc1 h loads/stores (hand-pipelined, counted vmcnt),
// relaxed flag atomics, and ZERO agent fences in the step loop.
// ---------------------------------------------------------------------------
__global__ __launch_bounds__(256, 1) void rnn_persist(
        const _Float16* __restrict__ X16,
        const _Float16* __restrict__ Bpack,
        _Float16* __restrict__ h_hi,   // [2][3][B][H]
        _Float16* __restrict__ h_lo,
        unsigned* __restrict__ flags,  // [192] monotonic step counters
        unsigned* __restrict__ epoch,  // [1]   monotonic
        const float* __restrict__ b_h,
        const float* __restrict__ b_layers,
        float* __restrict__ out) {

    const int wgid  = blockIdx.x;
    const int layer = wgid >> 6;
    const int g     = wgid & 63;
    const int n0    = g * 16;

    const int tid  = threadIdx.x;
    const int wave = tid >> 6;
    const int lane = tid & 63;
    const int rowm = wave * 16 + (lane & 15);   // batch row 0..63
    const int kq   = (lane >> 4) * 8;
    const size_t rowoffH = (size_t)rowm * HH + kq;

    // ---- stage this WG's weight slice into LDS (frag-packed, 64 KB) ----
    __shared__ __align__(16) _Float16 Bs[64 * 512];
    {
        const int nvec = (layer == 0) ? 40 * 64 : 64 * 64;   // uint4s
        const uint4* src = (const uint4*)(Bpack + (size_t)wgid * 32768);
        uint4* dst = (uint4*)Bs;
        for (int i = tid; i < nvec; i += 256) dst[i] = src[i];
    }
    __syncthreads();

    const float bv = (layer == 0) ? b_h[n0 + (lane & 15)]
                                  : b_layers[(size_t)(layer - 1) * HH + n0 + (lane & 15)];

    for (int t = 0; t < SS; ++t) {
        const int rb = t & 1;
        const _Float16* hi = h_hi + (size_t)rb * 3 * BH;
        const _Float16* lo = h_lo + (size_t)rb * 3 * BH;
        _Float16* nhi = h_hi + (size_t)(rb ^ 1) * 3 * BH;
        _Float16* nlo = h_lo + (size_t)(rb ^ 1) * 3 * BH;

        floatx4 accH = (floatx4){0.f, 0.f, 0.f, 0.f};
        floatx4 accL = (floatx4){0.f, 0.f, 0.f, 0.f};

        // compute one B-fragment block: acc += A(buf) * Bs[frag FB+i]
        #define COMP8(BH_, BL_, FB) do { \
            const half8* bsp = (const half8*)&Bs[(FB) * 512 + lane * 8]; \
            accH = MFMA16(BH_.a0, bsp[0*64], accH); accL = MFMA16(BL_.a0, bsp[0*64], accL); \
            accH = MFMA16(BH_.a1, bsp[1*64], accH); accL = MFMA16(BL_.a1, bsp[1*64], accL); \
            accH = MFMA16(BH_.a2, bsp[2*64], accH); accL = MFMA16(BL_.a2, bsp[2*64], accL); \
            accH = MFMA16(BH_.a3, bsp[3*64], accH); accL = MFMA16(BL_.a3, bsp[3*64], accL); \
            accH = MFMA16(BH_.a4, bsp[4*64], accH); accL = MFMA16(BL_.a4, bsp[4*64], accL); \
            accH = MFMA16(BH_.a5, bsp[5*64], accH); accL = MFMA16(BL_.a5, bsp[5*64], accL); \
            accH = MFMA16(BH_.a6, bsp[6*64], accH); accL = MFMA16(BL_.a6, bsp[6*64], accL); \
            accH = MFMA16(BH_.a7, bsp[7*64], accH); accL = MFMA16(BL_.a7, bsp[7*64], accL); \
        } while (0)

        // hand-pipelined coherent h-segment: 32 k-iters, hi+lo, 2 chunks deep
        auto hseg = [&](const _Float16* Ahi, const _Float16* Alo, int fb) {
            const _Float16* pH = Ahi + rowoffH;
            const _Float16* pL = Alo + rowoffH;
            B8 h0, l0, h1, l1;
            WAITV(0);                               // clean vmcnt baseline
            ISSUE8(h0, pH, 0);  ISSUE8(l0, pL, 0);
            ISSUE8(h1, pH, 8);  ISSUE8(l1, pL, 8);
            WAITV(16); COMP8(h0, l0, fb + 0);
            ISSUE8(h0, pH, 16); ISSUE8(l0, pL, 16);
            WAITV(16); COMP8(h1, l1, fb + 8);
            ISSUE8(h1, pH, 24); ISSUE8(l1, pL, 24);
            WAITV(16); COMP8(h0, l0, fb + 16);
            WAITV(0);  COMP8(h1, l1, fb + 24);
        };

        if (layer == 0) {
            // X segment: immutable data -> normal cached loads (L2-resident now)
            const _Float16* pX = X16 + (size_t)t * BB * II + (size_t)rowm * II + kq;
            #pragma unroll
            for (int ks = 0; ks < 8; ++ks) {
                const half8 a  = *(const half8*)(pX + ks * 32);
                const half8 bb = *(const half8*)&Bs[ks * 512 + lane * 8];
                accH = MFMA16(a, bb, accH);
            }
            hseg(hi + 0 * BH, lo + 0 * BH, 8);
        } else if (layer == 1) {
            hseg(hi + 1 * BH, lo + 1 * BH, 0);
            hseg(hi + 0 * BH, lo + 0 * BH, 32);
        } else {
            hseg(hi + 2 * BH, lo + 2 * BH, 0);
            hseg(hi + 1 * BH, lo + 1 * BH, 32);
        }

        // ---- finalize own 64x16 tile: bias, tanh, coherent h stores ----
        {
            const int n  = n0 + (lane & 15);
            const int mb = wave * 16 + (lane >> 4) * 4;
            #pragma unroll
            for (int rr = 0; rr < 4; ++rr) {
                const float v = tanhf(accH[rr] + accL[rr] + bv);
                const int m = mb + rr;
                const size_t hoff = (size_t)layer * BH + (size_t)m * HH + n;
                const _Float16 vh = (_Float16)v;
                const _Float16 vl = (_Float16)(v - (float)vh);
                const unsigned uhi = (unsigned)__builtin_bit_cast(unsigned short, vh);
                const unsigned ulo = (unsigned)__builtin_bit_cast(unsigned short, vl);
                ST2C(nhi + hoff, uhi);
                ST2C(nlo + hoff, ulo);
                if (layer == 2) out[(size_t)t * BH + (size_t)m * HH + n] = v;
                if (t == SS - 1)
                    out[(size_t)SS * BH + (size_t)layer * BH + (size_t)m * HH + n] = v;
            }
        }

        // ---- drain own stores, then hierarchical barrier (no fences) ----
        asm volatile("s_waitcnt vmcnt(0)" ::: "memory");
        __syncthreads();
        if (tid == 0)
            __hip_atomic_store(&flags[wgid], (unsigned)(t + 1),
                               __ATOMIC_RELAXED, __HIP_MEMORY_SCOPE_AGENT);
        if (wgid == 0) {
            if (tid < 192) {
                while (__hip_atomic_load(&flags[tid], __ATOMIC_RELAXED,
                                         __HIP_MEMORY_SCOPE_AGENT) < (unsigned)(t + 1))
                    __builtin_amdgcn_s_sleep(1);
            }
            __syncthreads();
            if (tid == 0)
                __hip_atomic_store(epoch, (unsigned)(t + 1),
                                   __ATOMIC_RELAXED, __HIP_MEMORY_SCOPE_AGENT);
        } else {
            if (tid == 0) {
                while (__hip_atomic_load(epoch, __ATOMIC_RELAXED,
                                         __HIP_MEMORY_SCOPE_AGENT) < (unsigned)(t + 1))
                    __builtin_amdgcn_s_sleep(2);
            }
        }
        __syncthreads();
        #undef COMP8
    }
}

// ---------------------------------------------------------------------------
extern "C" void kernel_launch(void* const* d_in, const int* in_sizes, int n_in,
                              void* d_out, int out_size, void* d_ws, size_t ws_size,
                              hipStream_t stream) {
    (void)in_sizes; (void)n_in; (void)out_size; (void)ws_size;
    const float* X   = (const float*)d_in[0];
    const float* Wxh = (const float*)d_in[1];
    const float* Whh = (const float*)d_in[2];
    const float* bh  = (const float*)d_in[3];
    const float* Wl  = (const float*)d_in[4];
    const float* Ul  = (const float*)d_in[5];
    const float* bl  = (const float*)d_in[6];
    float* out = (float*)d_out;

    char* ws = (char*)d_ws;
    _Float16* X16   = (_Float16*)(ws);                                   // 16,777,216 B
    _Float16* Bpack = (_Float16*)(ws + 16777216);                        // 12,582,912 B
    _Float16* h_hi  = (_Float16*)(ws + 16777216 + 12582912);             //    786,432 B
    _Float16* h_lo  = (_Float16*)(ws + 16777216 + 12582912 + 786432);    //    786,432 B
    unsigned* flags = (unsigned*)(ws + 16777216 + 12582912 + 2 * 786432); //    1,024 B

    hipLaunchKernelGGL(prep_misc,  dim3(4096), dim3(256), 0, stream, X, X16, h_hi, h_lo, flags);
    hipLaunchKernelGGL(prep_bpack, dim3(3072), dim3(256), 0, stream, Wxh, Whh, Wl, Ul, Bpack);
    hipLaunchKernelGGL(rnn_persist, dim3(192), dim3(256), 0, stream,
                       X16, Bpack, h_hi, h_lo, flags, flags + 192, bh, bl, out);
}

// Round 4
// 5456.043 us; speedup vs baseline: 4.4162x; 1.5941x over previous
//
#include <hip/hip_runtime.h>
#include <cmath>

#define SS 512
#define BB 64
#define II 256
#define HH 1024
#define BH (BB*HH)   // 65536

typedef _Float16 half8 __attribute__((ext_vector_type(8)));
typedef float    floatx4 __attribute__((ext_vector_type(4)));

// ---------------------------------------------------------------------------
// prep_misc: convert X fp32->fp16, zero h buffer 0 (hi+lo), zero flags/epoch
// ---------------------------------------------------------------------------
__global__ void prep_misc(const float* __restrict__ X, _Float16* __restrict__ X16,
                          _Float16* __restrict__ h_hi, _Float16* __restrict__ h_lo,
                          unsigned* __restrict__ flags) {
    const int tid = blockIdx.x * 256 + threadIdx.x;
    const size_t base = (size_t)tid * 8;   // 8 elems/thread covers 8,388,608 exactly
    #pragma unroll
    for (int j = 0; j < 8; ++j) X16[base + j] = (_Float16)X[base + j];
    if (tid < 49152) {
        ((unsigned long long*)h_hi)[tid] = 0ULL;
        ((unsigned long long*)h_lo)[tid] = 0ULL;
    }
    if (tid < 256) flags[tid] = 0u;   // flags[0..95], epoch at [192]
}

// ---------------------------------------------------------------------------
// prep_bpack: pack weights into MFMA B-fragment order, fp16.
// Unit u = (layer*16 + g)*8 + keid, u = 0..383: layer, 64-col group g,
// K-eighth keid (128 K of each segment). 32 frags/unit (layer0: 20).
//   layer>=1: f = seg*16 + kf*4 + cf   (seg0=U(h[layer]), seg1=W(h[layer-1]),
//             kf 0..3, cf = 16-col sub-block 0..3), k = keid*128 + kf*32 + kq
//   layer==0: f = cf (0..3): Wxh, k = keid*32 + kq   (X has K=256 total)
//             f = 4 + kf*4 + cf (4..19): Whh, k = keid*128 + kf*32 + kq
// Frag layout (16x16x32 f16 B): lane holds B[k=(lane>>4)*8+j][n=lane&15].
// 384 units x 32 frags x 64 lanes = 786,432 threads -> 3072 x 256.
// ---------------------------------------------------------------------------
__global__ void prep_bpack(const float* __restrict__ Wxh, const float* __restrict__ Whh,
                           const float* __restrict__ Wl,  const float* __restrict__ Ul,
                           _Float16* __restrict__ Bpack) {
    const int tid  = blockIdx.x * 256 + threadIdx.x;
    const int u    = tid >> 11;         // unit 0..383
    const int r    = tid & 2047;
    const int f    = r >> 5 >> 1;       // frag 0..31  (r>>6)
    const int lane = r & 63;
    const int keid = u & 7;
    const int w    = u >> 3;
    const int layer = w >> 4;
    const int g     = w & 15;
    const int cf = f & 3;
    const int n  = g * 64 + cf * 16 + (lane & 15);
    const int kq = (lane >> 4) * 8;
    const float* src;
    int k;
    if (layer == 0) {
        if (f >= 20) return;            // frags 20..31 unused for layer 0
        if (f < 4) { src = Wxh; k = keid * 32 + kq; }
        else       { src = Whh; k = keid * 128 + ((f - 4) >> 2) * 32 + kq; }
    } else {
        const int li  = layer - 1;
        const int seg = f >> 4;         // 0: U, 1: W
        const int kf  = (f >> 2) & 3;
        src = (seg ? Wl : Ul) + (size_t)li * HH * HH;
        k = keid * 128 + kf * 32 + kq;
    }
    _Float16* dst = Bpack + (size_t)u * 16384 + (size_t)f * 512 + (size_t)lane * 8;
    #pragma unroll
    for (int j = 0; j < 8; ++j) dst[j] = (_Float16)src[(size_t)(k + j) * HH + n];
}

// ---------------------------------------------------------------------------
// asm helpers (round-2 proven). All in-pipeline VMEM is inline asm so vmcnt
// counts are exact. sc1 = coherence-by-access at the Infinity-Cache point:
// no buffer_wbl2/buffer_inv anywhere in the step loop.
// ---------------------------------------------------------------------------
#define LD16C(dst, base, BYTEOFF) \
    asm volatile("global_load_dwordx4 %0, %1, off offset:%c2 sc1" \
                 : "=&v"(dst) : "v"(base), "n"(BYTEOFF))
#define LD16(dst, base, BYTEOFF) \
    asm volatile("global_load_dwordx4 %0, %1, off offset:%c2" \
                 : "=&v"(dst) : "v"(base), "n"(BYTEOFF))
#define LDB(dst, p) \
    asm volatile("global_load_dwordx4 %0, %1, off" : "=&v"(dst) : "v"(p))
#define LDF(dst, p) \
    asm volatile("global_load_dword %0, %1, off" : "=&v"(dst) : "v"(p))
#define WAITV(N) do { \
    asm volatile("s_waitcnt vmcnt(%c0)" :: "n"(N) : "memory"); \
    __builtin_amdgcn_sched_barrier(0); } while (0)
#define ST2C(p, u32) \
    asm volatile("global_store_short %0, %1, off sc1" :: "v"(p), "v"(u32) : "memory")

#define MFMA16(A, B, C) __builtin_amdgcn_mfma_f32_16x16x32_f16(A, B, C, 0, 0, 0)

struct KB { half8 h0, h1, l0, l1; };   // one k-frag: rf0/rf1 x hi/lo (4 loads)

#define ISS(Kb, PH0, PH1, PL0, PL1, KF) do { \
    LD16C(Kb.h0, PH0, (KF)*64); LD16C(Kb.h1, PH1, (KF)*64); \
    LD16C(Kb.l0, PL0, (KF)*64); LD16C(Kb.l1, PL1, (KF)*64); } while (0)

// 16 MFMA per k-frag: hi rf0, hi rf1, lo rf0, lo rf1 (chains at distance 8)
#define CMP(Kb, FB) do { \
    a00 = MFMA16(Kb.h0, b[(FB)+0], a00); a01 = MFMA16(Kb.h0, b[(FB)+1], a01); \
    a02 = MFMA16(Kb.h0, b[(FB)+2], a02); a03 = MFMA16(Kb.h0, b[(FB)+3], a03); \
    a10 = MFMA16(Kb.h1, b[(FB)+0], a10); a11 = MFMA16(Kb.h1, b[(FB)+1], a11); \
    a12 = MFMA16(Kb.h1, b[(FB)+2], a12); a13 = MFMA16(Kb.h1, b[(FB)+3], a13); \
    a00 = MFMA16(Kb.l0, b[(FB)+0], a00); a01 = MFMA16(Kb.l0, b[(FB)+1], a01); \
    a02 = MFMA16(Kb.l0, b[(FB)+2], a02); a03 = MFMA16(Kb.l0, b[(FB)+3], a03); \
    a10 = MFMA16(Kb.l1, b[(FB)+0], a10); a11 = MFMA16(Kb.l1, b[(FB)+1], a11); \
    a12 = MFMA16(Kb.l1, b[(FB)+2], a12); a13 = MFMA16(Kb.l1, b[(FB)+3], a13); } while (0)
// X segment (no lo part), frags 0..3
#define CMPX(Kb) do { \
    a00 = MFMA16(Kb.h0, b[0], a00); a01 = MFMA16(Kb.h0, b[1], a01); \
    a02 = MFMA16(Kb.h0, b[2], a02); a03 = MFMA16(Kb.h0, b[3], a03); \
    a10 = MFMA16(Kb.h1, b[0], a10); a11 = MFMA16(Kb.h1, b[1], a11); \
    a12 = MFMA16(Kb.h1, b[2], a12); a13 = MFMA16(Kb.h1, b[3], a13); } while (0)

// ---------------------------------------------------------------------------
// Persistent RNN: 96 WGs x 512 threads (8 waves = 2/SIMD).
// WG = (layer, 64-col group, 32-row half). Wave = K-eighth (128 K per seg).
// B-weights: 32 frags = 128 VGPR/wave (loaded once, reused 512 steps).
// A-stream: sc1 loads, 3-deep counted-vmcnt pipeline (12 in flight).
// K-eighth partials reduced via 64KB LDS; round-2-proven barrier.
// ---------------------------------------------------------------------------
__global__ __launch_bounds__(512, 2) void rnn_persist(
        const _Float16* __restrict__ X16,
        const _Float16* __restrict__ Bpack,
        _Float16* __restrict__ h_hi,   // [2][3][B][H]
        _Float16* __restrict__ h_lo,
        unsigned* __restrict__ flags,  // [96] monotonic step counters
        unsigned* __restrict__ epoch,  // [1]
        const float* __restrict__ b_h,
        const float* __restrict__ b_layers,
        float* __restrict__ out) {

    const int wgid  = blockIdx.x;          // 0..95
    const int layer = wgid >> 5;
    const int rem   = wgid & 31;
    const int cg    = rem >> 1;            // col group 0..15 (64 cols)
    const int rh    = rem & 1;             // row half (32 rows)
    const int n0    = cg * 64;
    const int m0    = rh * 32;

    const int tid   = threadIdx.x;
    const int keid  = tid >> 6;            // wave = K-eighth 0..7
    const int lane  = tid & 63;
    const int rlane = lane & 15;
    const int kq8   = (lane >> 4) * 8;

    __shared__ __align__(16) floatx4 Rbuf[8 * 8 * 64];   // 64 KB: [wave][frag][lane]

    // ---- B weights -> registers (32 frags = 128 VGPR; layer0 uses 20) ----
    half8 b[32];
    {
        const _Float16* Bq = Bpack + (size_t)((wgid >> 1) * 8 + keid) * 16384
                                   + (size_t)lane * 8;
        if (layer == 0) {
            #pragma unroll
            for (int f = 0; f < 20; ++f) LDB(b[f], Bq + f * 512);
        } else {
            #pragma unroll
            for (int f = 0; f < 32; ++f) LDB(b[f], Bq + f * 512);
        }
    }
    // ---- bias (4 cols per lane, one per cf) ----
    float bv0, bv1, bv2, bv3;
    {
        const float* bp = (layer == 0 ? b_h : b_layers + (size_t)(layer - 1) * HH)
                          + n0 + rlane;
        LDF(bv0, bp); LDF(bv1, bp + 16); LDF(bv2, bp + 32); LDF(bv3, bp + 48);
    }
    WAITV(0);
    __syncthreads();

    const size_t rowA = (size_t)(m0 + rlane) * HH + (size_t)keid * 128 + kq8;
    const size_t segA = (size_t)layer * BH;                       // h[layer]
    const size_t segB = (size_t)(layer > 0 ? layer - 1 : 0) * BH; // h[layer-1]
    const size_t xoff = (size_t)(m0 + rlane) * II + keid * 32 + kq8;

    const floatx4 zf = (floatx4){0.f, 0.f, 0.f, 0.f};

    for (int t = 0; t < SS; ++t) {
        const int rb = t & 1;
        const _Float16* hi = h_hi + (size_t)rb * 3 * BH;
        const _Float16* lo = h_lo + (size_t)rb * 3 * BH;
        _Float16* nhi = h_hi + (size_t)(rb ^ 1) * 3 * BH;
        _Float16* nlo = h_lo + (size_t)(rb ^ 1) * 3 * BH;
        const _Float16* pAh0 = hi + segA + rowA; const _Float16* pAh1 = pAh0 + 16 * HH;
        const _Float16* pAl0 = lo + segA + rowA; const _Float16* pAl1 = pAl0 + 16 * HH;
        const _Float16* pBh0 = hi + segB + rowA; const _Float16* pBh1 = pBh0 + 16 * HH;
        const _Float16* pBl0 = lo + segB + rowA; const _Float16* pBl1 = pBl0 + 16 * HH;

        floatx4 a00 = zf, a01 = zf, a02 = zf, a03 = zf;
        floatx4 a10 = zf, a11 = zf, a12 = zf, a13 = zf;
        KB K0, K1, K2;

        if (layer == 0) {
            KB XB;
            const _Float16* pX0 = X16 + (size_t)t * BB * II + xoff;
            const _Float16* pX1 = pX0 + 16 * II;
            LD16(XB.h0, pX0, 0); LD16(XB.h1, pX1, 0);             // 2 out
            ISS(K0, pAh0, pAh1, pAl0, pAl1, 0);                   // 6
            ISS(K1, pAh0, pAh1, pAl0, pAl1, 1);                   // 10
            WAITV(8); CMPX(XB);
            ISS(K2, pAh0, pAh1, pAl0, pAl1, 2);                   // 12
            WAITV(8); CMP(K0,  4); ISS(K0, pAh0, pAh1, pAl0, pAl1, 3);
            WAITV(8); CMP(K1,  8);
            WAITV(4); CMP(K2, 12);
            WAITV(0); CMP(K0, 16);
        } else {
            ISS(K0, pAh0, pAh1, pAl0, pAl1, 0);
            ISS(K1, pAh0, pAh1, pAl0, pAl1, 1);
            ISS(K2, pAh0, pAh1, pAl0, pAl1, 2);                   // 12 out
            WAITV(8); CMP(K0,  0); ISS(K0, pAh0, pAh1, pAl0, pAl1, 3);
            WAITV(8); CMP(K1,  4); ISS(K1, pBh0, pBh1, pBl0, pBl1, 0);
            WAITV(8); CMP(K2,  8); ISS(K2, pBh0, pBh1, pBl0, pBl1, 1);
            WAITV(8); CMP(K0, 12); ISS(K0, pBh0, pBh1, pBl0, pBl1, 2);
            WAITV(8); CMP(K1, 16); ISS(K1, pBh0, pBh1, pBl0, pBl1, 3);
            WAITV(8); CMP(K2, 20);
            WAITV(4); CMP(K0, 24);
            WAITV(0); CMP(K1, 28);
        }

        // ---- cross-wave K-eighth reduction through LDS ----
        Rbuf[(keid * 8 + 0) * 64 + lane] = a00;
        Rbuf[(keid * 8 + 1) * 64 + lane] = a01;
        Rbuf[(keid * 8 + 2) * 64 + lane] = a02;
        Rbuf[(keid * 8 + 3) * 64 + lane] = a03;
        Rbuf[(keid * 8 + 4) * 64 + lane] = a10;
        Rbuf[(keid * 8 + 5) * 64 + lane] = a11;
        Rbuf[(keid * 8 + 6) * 64 + lane] = a12;
        Rbuf[(keid * 8 + 7) * 64 + lane] = a13;
        __syncthreads();

        // ---- wave keid finalizes output frag fo = keid ----
        {
            const int fo = keid;                       // wave-uniform
            floatx4 s = Rbuf[fo * 64 + lane];
            #pragma unroll
            for (int wv = 1; wv < 8; ++wv)
                s += Rbuf[(wv * 8 + fo) * 64 + lane];
            const int rf = fo >> 2, cf = fo & 3;       // wave-uniform
            const float bvv = cf == 0 ? bv0 : cf == 1 ? bv1 : cf == 2 ? bv2 : bv3;
            const int n  = n0 + cf * 16 + rlane;
            const int mb = m0 + rf * 16 + (lane >> 4) * 4;
            #pragma unroll
            for (int rr = 0; rr < 4; ++rr) {
                const float v = tanhf(s[rr] + bvv);
                const int m = mb + rr;
                const size_t hoff = (size_t)layer * BH + (size_t)m * HH + n;
                const _Float16 vh = (_Float16)v;
                const _Float16 vl = (_Float16)(v - (float)vh);
                ST2C(nhi + hoff, (unsigned)__builtin_bit_cast(unsigned short, vh));
                ST2C(nlo + hoff, (unsigned)__builtin_bit_cast(unsigned short, vl));
                if (layer == 2) out[(size_t)t * BH + (size_t)m * HH + n] = v;
                if (t == SS - 1)
                    out[(size_t)SS * BH + (size_t)layer * BH + (size_t)m * HH + n] = v;
            }
        }

        // ---- drain stores, hierarchical barrier (round-2 exact, no fences) ----
        asm volatile("s_waitcnt vmcnt(0)" ::: "memory");
        __syncthreads();
        if (tid == 0)
            __hip_atomic_store(&flags[wgid], (unsigned)(t + 1),
                               __ATOMIC_RELAXED, __HIP_MEMORY_SCOPE_AGENT);
        if (wgid == 0) {
            if (tid < 96) {
                while (__hip_atomic_load(&flags[tid], __ATOMIC_RELAXED,
                                         __HIP_MEMORY_SCOPE_AGENT) < (unsigned)(t + 1))
                    __builtin_amdgcn_s_sleep(1);
            }
            __syncthreads();
            if (tid == 0)
                __hip_atomic_store(epoch, (unsigned)(t + 1),
                                   __ATOMIC_RELAXED, __HIP_MEMORY_SCOPE_AGENT);
        } else {
            if (tid == 0) {
                while (__hip_atomic_load(epoch, __ATOMIC_RELAXED,
                                         __HIP_MEMORY_SCOPE_AGENT) < (unsigned)(t + 1))
                    __builtin_amdgcn_s_sleep(2);
            }
        }
        __syncthreads();
    }
}

// ---------------------------------------------------------------------------
extern "C" void kernel_launch(void* const* d_in, const int* in_sizes, int n_in,
                              void* d_out, int out_size, void* d_ws, size_t ws_size,
                              hipStream_t stream) {
    (void)in_sizes; (void)n_in; (void)out_size; (void)ws_size;
    const float* X   = (const float*)d_in[0];
    const float* Wxh = (const float*)d_in[1];
    const float* Whh = (const float*)d_in[2];
    const float* bh  = (const float*)d_in[3];
    const float* Wl  = (const float*)d_in[4];
    const float* Ul  = (const float*)d_in[5];
    const float* bl  = (const float*)d_in[6];
    float* out = (float*)d_out;

    char* ws = (char*)d_ws;
    _Float16* X16   = (_Float16*)(ws);                                   // 16,777,216 B
    _Float16* Bpack = (_Float16*)(ws + 16777216);                        // 12,582,912 B
    _Float16* h_hi  = (_Float16*)(ws + 16777216 + 12582912);             //    786,432 B
    _Float16* h_lo  = (_Float16*)(ws + 16777216 + 12582912 + 786432);    //    786,432 B
    unsigned* flags = (unsigned*)(ws + 16777216 + 12582912 + 2 * 786432); //    1,024 B

    hipLaunchKernelGGL(prep_misc,  dim3(4096), dim3(256), 0, stream, X, X16, h_hi, h_lo, flags);
    hipLaunchKernelGGL(prep_bpack, dim3(3072), dim3(256), 0, stream, Wxh, Whh, Wl, Ul, Bpack);
    hipLaunchKernelGGL(rnn_persist, dim3(96), dim3(512), 0, stream,
                       X16, Bpack, h_hi, h_lo, flags, flags + 192, bh, bl, out);
}

// Round 5
// 4861.458 us; speedup vs baseline: 4.9563x; 1.1223x over previous
//
#include <hip/hip_runtime.h>
#include <cmath>

#define SS 512
#define BB 64
#define II 256
#define HH 1024
#define BH (BB*HH)   // 65536

typedef _Float16 half8 __attribute__((ext_vector_type(8)));
typedef float    floatx4 __attribute__((ext_vector_type(4)));

// ---------------------------------------------------------------------------
// prep_misc: convert X fp32->fp16, zero h buffer 0 (hi+lo), zero flags
// ---------------------------------------------------------------------------
__global__ void prep_misc(const float* __restrict__ X, _Float16* __restrict__ X16,
                          _Float16* __restrict__ h_hi, _Float16* __restrict__ h_lo,
                          unsigned* __restrict__ flags) {
    const int tid = blockIdx.x * 256 + threadIdx.x;
    const size_t base = (size_t)tid * 8;   // 8 elems/thread covers 8,388,608 exactly
    #pragma unroll
    for (int j = 0; j < 8; ++j) X16[base + j] = (_Float16)X[base + j];
    if (tid < 49152) {
        ((unsigned long long*)h_hi)[tid] = 0ULL;
        ((unsigned long long*)h_lo)[tid] = 0ULL;
    }
    if (tid < 256) flags[tid] = 0u;   // flags[0..191]
}

// ---------------------------------------------------------------------------
// prep_bpack: pack weights into MFMA B-fragment order, fp16. (UNCHANGED from
// round 4 -- row-split WGs share B units.)
// Unit u = (layer*16 + g)*8 + keid, u = 0..383. 32 frags/unit (layer0: 20).
//   layer>=1: f = seg*16 + kf*4 + cf  (seg0=U(h[layer]), seg1=W(h[layer-1]))
//   layer==0: f = cf (0..3): Wxh;  f = 4 + kf*4 + cf (4..19): Whh
// Frag layout (16x16x32 f16 B): lane holds B[k=(lane>>4)*8+j][n=lane&15].
// ---------------------------------------------------------------------------
__global__ void prep_bpack(const float* __restrict__ Wxh, const float* __restrict__ Whh,
                           const float* __restrict__ Wl,  const float* __restrict__ Ul,
                           _Float16* __restrict__ Bpack) {
    const int tid  = blockIdx.x * 256 + threadIdx.x;
    const int u    = tid >> 11;         // unit 0..383
    const int r    = tid & 2047;
    const int f    = r >> 6;            // frag 0..31
    const int lane = r & 63;
    const int keid = u & 7;
    const int w    = u >> 3;
    const int layer = w >> 4;
    const int g     = w & 15;
    const int cf = f & 3;
    const int n  = g * 64 + cf * 16 + (lane & 15);
    const int kq = (lane >> 4) * 8;
    const float* src;
    int k;
    if (layer == 0) {
        if (f >= 20) return;            // frags 20..31 unused for layer 0
        if (f < 4) { src = Wxh; k = keid * 32 + kq; }
        else       { src = Whh; k = keid * 128 + ((f - 4) >> 2) * 32 + kq; }
    } else {
        const int li  = layer - 1;
        const int seg = f >> 4;         // 0: U, 1: W
        const int kf  = (f >> 2) & 3;
        src = (seg ? Wl : Ul) + (size_t)li * HH * HH;
        k = keid * 128 + kf * 32 + kq;
    }
    _Float16* dst = Bpack + (size_t)u * 16384 + (size_t)f * 512 + (size_t)lane * 8;
    #pragma unroll
    for (int j = 0; j < 8; ++j) dst[j] = (_Float16)src[(size_t)(k + j) * HH + n];
}

// ---------------------------------------------------------------------------
// asm helpers (round-2/4 proven). All in-pipeline VMEM is inline asm so vmcnt
// counts are exact. sc1 = coherence-by-access at the Infinity-Cache point:
// no buffer_wbl2/buffer_inv anywhere in the step loop.
// ---------------------------------------------------------------------------
#define LD16C(dst, base, BYTEOFF) \
    asm volatile("global_load_dwordx4 %0, %1, off offset:%c2 sc1" \
                 : "=&v"(dst) : "v"(base), "n"(BYTEOFF))
#define LD16(dst, base, BYTEOFF) \
    asm volatile("global_load_dwordx4 %0, %1, off offset:%c2" \
                 : "=&v"(dst) : "v"(base), "n"(BYTEOFF))
#define LDB(dst, p) \
    asm volatile("global_load_dwordx4 %0, %1, off" : "=&v"(dst) : "v"(p))
#define LDF(dst, p) \
    asm volatile("global_load_dword %0, %1, off" : "=&v"(dst) : "v"(p))
#define WAITV(N) do { \
    asm volatile("s_waitcnt vmcnt(%c0)" :: "n"(N) : "memory"); \
    __builtin_amdgcn_sched_barrier(0); } while (0)
#define ST2C(p, u32) \
    asm volatile("global_store_short %0, %1, off sc1" :: "v"(p), "v"(u32) : "memory")

#define MFMA16(A, B, C) __builtin_amdgcn_mfma_f32_16x16x32_f16(A, B, C, 0, 0, 0)

struct KB2 { half8 h, l; };   // one k-frag: single rf, hi+lo (2 loads)

#define ISS2(Kb, PH, PL, KF) do { \
    LD16C(Kb.h, PH, (KF)*64); LD16C(Kb.l, PL, (KF)*64); } while (0)

// 8 MFMA per k-frag: hi over cf 0..3, then lo (acc chains at distance 4)
#define CMP2(Kb, FB) do { \
    a0 = MFMA16(Kb.h, b[(FB)+0], a0); a1 = MFMA16(Kb.h, b[(FB)+1], a1); \
    a2 = MFMA16(Kb.h, b[(FB)+2], a2); a3 = MFMA16(Kb.h, b[(FB)+3], a3); \
    a0 = MFMA16(Kb.l, b[(FB)+0], a0); a1 = MFMA16(Kb.l, b[(FB)+1], a1); \
    a2 = MFMA16(Kb.l, b[(FB)+2], a2); a3 = MFMA16(Kb.l, b[(FB)+3], a3); } while (0)
// X segment (no lo part), frags 0..3
#define CMPX2(Xr) do { \
    a0 = MFMA16(Xr, b[0], a0); a1 = MFMA16(Xr, b[1], a1); \
    a2 = MFMA16(Xr, b[2], a2); a3 = MFMA16(Xr, b[3], a3); } while (0)

// ---------------------------------------------------------------------------
// Persistent RNN: 192 WGs x 512 threads (8 waves = 2/SIMD, 192 CUs active).
// WG = (layer, 64-col group, 16-row quarter). Wave = K-eighth (128 K/seg).
// B-weights: 32 frags = 128 VGPR/wave (loaded once, reused 512 steps).
// A-stream: sc1 loads, 4-buffer counted-vmcnt pipeline (8 in flight).
// K-eighth partials reduced via 32KB LDS; flat 1-hop flag barrier.
// ---------------------------------------------------------------------------
__global__ __launch_bounds__(512, 2) void rnn_persist(
        const _Float16* __restrict__ X16,
        const _Float16* __restrict__ Bpack,
        _Float16* __restrict__ h_hi,   // [2][3][B][H]
        _Float16* __restrict__ h_lo,
        unsigned* __restrict__ flags,  // [192] monotonic step counters
        unsigned* __restrict__ epoch,  // unused (kept for signature)
        const float* __restrict__ b_h,
        const float* __restrict__ b_layers,
        float* __restrict__ out) {
    (void)epoch;

    const int wgid  = blockIdx.x;          // 0..191
    const int layer = wgid >> 6;
    const int cg    = (wgid >> 2) & 15;    // col group 0..15 (64 cols)
    const int rq    = wgid & 3;            // row quarter (16 rows)
    const int n0    = cg * 64;
    const int m0    = rq * 16;

    const int tid   = threadIdx.x;
    const int keid  = tid >> 6;            // wave = K-eighth 0..7
    const int lane  = tid & 63;
    const int rlane = lane & 15;
    const int kq8   = (lane >> 4) * 8;

    __shared__ __align__(16) floatx4 Rbuf[8 * 4 * 64];   // 32 KB: [wave][frag][lane]

    // ---- B weights -> registers (32 frags = 128 VGPR; layer0 uses 20) ----
    half8 b[32];
    {
        const _Float16* Bq = Bpack + (size_t)((wgid >> 2) * 8 + keid) * 16384
                                   + (size_t)lane * 8;
        if (layer == 0) {
            #pragma unroll
            for (int f = 0; f < 20; ++f) LDB(b[f], Bq + f * 512);
        } else {
            #pragma unroll
            for (int f = 0; f < 32; ++f) LDB(b[f], Bq + f * 512);
        }
    }
    // ---- bias: this wave finalizes col sub-block fo = keid>>1 ----
    const int fo    = keid >> 1;           // output frag 0..3 (wave-uniform)
    const int rhalf = keid & 1;            // row pair within frag
    float bvv;
    {
        const float* bp = (layer == 0 ? b_h : b_layers + (size_t)(layer - 1) * HH)
                          + n0 + fo * 16 + rlane;
        LDF(bvv, bp);
    }
    WAITV(0);
    __syncthreads();

    const size_t rowA = (size_t)(m0 + rlane) * HH + (size_t)keid * 128 + kq8;
    const size_t segA = (size_t)layer * BH;                       // h[layer]
    const size_t segB = (size_t)(layer > 0 ? layer - 1 : 0) * BH; // h[layer-1]
    const size_t xoff = (size_t)(m0 + rlane) * II + keid * 32 + kq8;

    const floatx4 zf = (floatx4){0.f, 0.f, 0.f, 0.f};

    for (int t = 0; t < SS; ++t) {
        const int rb = t & 1;
        const _Float16* hi = h_hi + (size_t)rb * 3 * BH;
        const _Float16* lo = h_lo + (size_t)rb * 3 * BH;
        _Float16* nhi = h_hi + (size_t)(rb ^ 1) * 3 * BH;
        _Float16* nlo = h_lo + (size_t)(rb ^ 1) * 3 * BH;
        const _Float16* pAh = hi + segA + rowA;
        const _Float16* pAl = lo + segA + rowA;
        const _Float16* pBh = hi + segB + rowA;
        const _Float16* pBl = lo + segB + rowA;

        floatx4 a0 = zf, a1 = zf, a2 = zf, a3 = zf;
        KB2 K0, K1, K2, K3;

        if (layer == 0) {
            half8 xr;
            const _Float16* pX = X16 + (size_t)t * BB * II + xoff;
            LD16(xr, pX, 0);                                      // 1 out
            ISS2(K0, pAh, pAl, 0);                                // 3
            ISS2(K1, pAh, pAl, 1);                                // 5
            ISS2(K2, pAh, pAl, 2);                                // 7
            ISS2(K3, pAh, pAl, 3);                                // 9
            WAITV(8); CMPX2(xr);
            WAITV(6); CMP2(K0,  4);
            WAITV(4); CMP2(K1,  8);
            WAITV(2); CMP2(K2, 12);
            WAITV(0); CMP2(K3, 16);
        } else {
            ISS2(K0, pAh, pAl, 0);
            ISS2(K1, pAh, pAl, 1);
            ISS2(K2, pAh, pAl, 2);
            ISS2(K3, pAh, pAl, 3);                                // 8 out
            WAITV(6); CMP2(K0,  0); ISS2(K0, pBh, pBl, 0);
            WAITV(6); CMP2(K1,  4); ISS2(K1, pBh, pBl, 1);
            WAITV(6); CMP2(K2,  8); ISS2(K2, pBh, pBl, 2);
            WAITV(6); CMP2(K3, 12); ISS2(K3, pBh, pBl, 3);
            WAITV(6); CMP2(K0, 16);
            WAITV(4); CMP2(K1, 20);
            WAITV(2); CMP2(K2, 24);
            WAITV(0); CMP2(K3, 28);
        }

        // ---- cross-wave K-eighth reduction through LDS ----
        Rbuf[(keid * 4 + 0) * 64 + lane] = a0;
        Rbuf[(keid * 4 + 1) * 64 + lane] = a1;
        Rbuf[(keid * 4 + 2) * 64 + lane] = a2;
        Rbuf[(keid * 4 + 3) * 64 + lane] = a3;
        __syncthreads();

        // ---- wave keid finalizes frag fo=keid>>1, row pair rhalf ----
        {
            floatx4 s = Rbuf[fo * 64 + lane];
            #pragma unroll
            for (int wv = 1; wv < 8; ++wv)
                s += Rbuf[(wv * 4 + fo) * 64 + lane];
            const int n  = n0 + fo * 16 + rlane;
            const int mb = m0 + (lane >> 4) * 4 + rhalf * 2;
            #pragma unroll
            for (int rr = 0; rr < 2; ++rr) {
                const float v = tanhf(s[rhalf * 2 + rr] + bvv);
                const int m = mb + rr;
                const size_t hoff = (size_t)layer * BH + (size_t)m * HH + n;
                const _Float16 vh = (_Float16)v;
                const _Float16 vl = (_Float16)(v - (float)vh);
                ST2C(nhi + hoff, (unsigned)__builtin_bit_cast(unsigned short, vh));
                ST2C(nlo + hoff, (unsigned)__builtin_bit_cast(unsigned short, vl));
                if (layer == 2) out[(size_t)t * BH + (size_t)m * HH + n] = v;
                if (t == SS - 1)
                    out[(size_t)SS * BH + (size_t)layer * BH + (size_t)m * HH + n] = v;
            }
        }

        // ---- drain stores, flat 1-hop flag barrier (no fences) ----
        asm volatile("s_waitcnt vmcnt(0)" ::: "memory");
        __syncthreads();
        if (tid == 0)
            __hip_atomic_store(&flags[wgid], (unsigned)(t + 1),
                               __ATOMIC_RELAXED, __HIP_MEMORY_SCOPE_AGENT);
        if (tid < 192) {
            while (__hip_atomic_load(&flags[tid], __ATOMIC_RELAXED,
                                     __HIP_MEMORY_SCOPE_AGENT) < (unsigned)(t + 1))
                __builtin_amdgcn_s_sleep(1);
        }
        __syncthreads();
    }
}

// ---------------------------------------------------------------------------
extern "C" void kernel_launch(void* const* d_in, const int* in_sizes, int n_in,
                              void* d_out, int out_size, void* d_ws, size_t ws_size,
                              hipStream_t stream) {
    (void)in_sizes; (void)n_in; (void)out_size; (void)ws_size;
    const float* X   = (const float*)d_in[0];
    const float* Wxh = (const float*)d_in[1];
    const float* Whh = (const float*)d_in[2];
    const float* bh  = (const float*)d_in[3];
    const float* Wl  = (const float*)d_in[4];
    const float* Ul  = (const float*)d_in[5];
    const float* bl  = (const float*)d_in[6];
    float* out = (float*)d_out;

    char* ws = (char*)d_ws;
    _Float16* X16   = (_Float16*)(ws);                                   // 16,777,216 B
    _Float16* Bpack = (_Float16*)(ws + 16777216);                        // 12,582,912 B
    _Float16* h_hi  = (_Float16*)(ws + 16777216 + 12582912);             //    786,432 B
    _Float16* h_lo  = (_Float16*)(ws + 16777216 + 12582912 + 786432);    //    786,432 B
    unsigned* flags = (unsigned*)(ws + 16777216 + 12582912 + 2 * 786432); //    1,024 B

    hipLaunchKernelGGL(prep_misc,  dim3(4096), dim3(256), 0, stream, X, X16, h_hi, h_lo, flags);
    hipLaunchKernelGGL(prep_bpack, dim3(3072), dim3(256), 0, stream, Wxh, Whh, Wl, Ul, Bpack);
    hipLaunchKernelGGL(rnn_persist, dim3(192), dim3(512), 0, stream,
                       X16, Bpack, h_hi, h_lo, flags, flags + 192, bh, bl, out);
}

// Round 6
// 4051.709 us; speedup vs baseline: 5.9468x; 1.1999x over previous
//
#include <hip/hip_runtime.h>
#include <cmath>

#define SS 512
#define BB 64
#define II 256
#define HH 1024
#define BH (BB*HH)   // 65536

typedef _Float16 half8 __attribute__((ext_vector_type(8)));
typedef float    floatx4 __attribute__((ext_vector_type(4)));

// ---------------------------------------------------------------------------
// prep_misc: convert X fp32->fp16, zero h buffer 0 (hi+lo), zero flags
// ---------------------------------------------------------------------------
__global__ void prep_misc(const float* __restrict__ X, _Float16* __restrict__ X16,
                          _Float16* __restrict__ h_hi, _Float16* __restrict__ h_lo,
                          unsigned* __restrict__ flags) {
    const int tid = blockIdx.x * 256 + threadIdx.x;
    const size_t base = (size_t)tid * 8;   // 8 elems/thread covers 8,388,608 exactly
    #pragma unroll
    for (int j = 0; j < 8; ++j) X16[base + j] = (_Float16)X[base + j];
    if (tid < 49152) {
        ((unsigned long long*)h_hi)[tid] = 0ULL;
        ((unsigned long long*)h_lo)[tid] = 0ULL;
    }
    if (tid < 256) flags[tid] = 0u;   // flags[0..191]
}

// ---------------------------------------------------------------------------
// prep_bpack: pack weights into MFMA B-fragment order, fp16. (UNCHANGED from
// round 4/5 -- row-split WGs share B units.)
// Unit u = (layer*16 + g)*8 + keid, u = 0..383. 32 frags/unit (layer0: 20).
//   layer>=1: f = seg*16 + kf*4 + cf  (seg0=U(h[layer]), seg1=W(h[layer-1]))
//   layer==0: f = cf (0..3): Wxh;  f = 4 + kf*4 + cf (4..19): Whh
// Frag layout (16x16x32 f16 B): lane holds B[k=(lane>>4)*8+j][n=lane&15].
// ---------------------------------------------------------------------------
__global__ void prep_bpack(const float* __restrict__ Wxh, const float* __restrict__ Whh,
                           const float* __restrict__ Wl,  const float* __restrict__ Ul,
                           _Float16* __restrict__ Bpack) {
    const int tid  = blockIdx.x * 256 + threadIdx.x;
    const int u    = tid >> 11;         // unit 0..383
    const int r    = tid & 2047;
    const int f    = r >> 6;            // frag 0..31
    const int lane = r & 63;
    const int keid = u & 7;
    const int w    = u >> 3;
    const int layer = w >> 4;
    const int g     = w & 15;
    const int cf = f & 3;
    const int n  = g * 64 + cf * 16 + (lane & 15);
    const int kq = (lane >> 4) * 8;
    const float* src;
    int k;
    if (layer == 0) {
        if (f >= 20) return;            // frags 20..31 unused for layer 0
        if (f < 4) { src = Wxh; k = keid * 32 + kq; }
        else       { src = Whh; k = keid * 128 + ((f - 4) >> 2) * 32 + kq; }
    } else {
        const int li  = layer - 1;
        const int seg = f >> 4;         // 0: U, 1: W
        const int kf  = (f >> 2) & 3;
        src = (seg ? Wl : Ul) + (size_t)li * HH * HH;
        k = keid * 128 + kf * 32 + kq;
    }
    _Float16* dst = Bpack + (size_t)u * 16384 + (size_t)f * 512 + (size_t)lane * 8;
    #pragma unroll
    for (int j = 0; j < 8; ++j) dst[j] = (_Float16)src[(size_t)(k + j) * HH + n];
}

// ---------------------------------------------------------------------------
// asm helpers (round-2/4/5 proven). All in-pipeline VMEM is inline asm so
// vmcnt counts are exact. sc1 = coherence-by-access at the Infinity-Cache
// point: no buffer_wbl2/buffer_inv anywhere in the step loop.
// ---------------------------------------------------------------------------
#define LD16C(dst, base, BYTEOFF) \
    asm volatile("global_load_dwordx4 %0, %1, off offset:%c2 sc1" \
                 : "=&v"(dst) : "v"(base), "n"(BYTEOFF))
#define LD16(dst, base, BYTEOFF) \
    asm volatile("global_load_dwordx4 %0, %1, off offset:%c2" \
                 : "=&v"(dst) : "v"(base), "n"(BYTEOFF))
#define LDB(dst, p) \
    asm volatile("global_load_dwordx4 %0, %1, off" : "=&v"(dst) : "v"(p))
#define LDF(dst, p) \
    asm volatile("global_load_dword %0, %1, off" : "=&v"(dst) : "v"(p))
#define WAITV(N) do { \
    asm volatile("s_waitcnt vmcnt(%c0)" :: "n"(N) : "memory"); \
    __builtin_amdgcn_sched_barrier(0); } while (0)
#define ST2C(p, u32) \
    asm volatile("global_store_short %0, %1, off sc1" :: "v"(p), "v"(u32) : "memory")

#define MFMA16(A, B, C) __builtin_amdgcn_mfma_f32_16x16x32_f16(A, B, C, 0, 0, 0)

struct KB2 { half8 h, l; };   // one k-frag: single rf, hi+lo (2 loads)

#define ISS2(Kb, PH, PL, KF) do { \
    LD16C(Kb.h, PH, (KF)*64); LD16C(Kb.l, PL, (KF)*64); } while (0)

// 8 MFMA per k-frag: hi over cf 0..3, then lo (acc chains at distance 4)
#define CMP2(Kb, FB) do { \
    a0 = MFMA16(Kb.h, b[(FB)+0], a0); a1 = MFMA16(Kb.h, b[(FB)+1], a1); \
    a2 = MFMA16(Kb.h, b[(FB)+2], a2); a3 = MFMA16(Kb.h, b[(FB)+3], a3); \
    a0 = MFMA16(Kb.l, b[(FB)+0], a0); a1 = MFMA16(Kb.l, b[(FB)+1], a1); \
    a2 = MFMA16(Kb.l, b[(FB)+2], a2); a3 = MFMA16(Kb.l, b[(FB)+3], a3); } while (0)
// X segment (no lo part), frags 0..3
#define CMPX2(Xr) do { \
    a0 = MFMA16(Xr, b[0], a0); a1 = MFMA16(Xr, b[1], a1); \
    a2 = MFMA16(Xr, b[2], a2); a3 = MFMA16(Xr, b[3], a3); } while (0)

// ---------------------------------------------------------------------------
// Persistent RNN: 192 WGs x 512 threads (8 waves = 2/SIMD, 192 CUs active).
// WG = (layer, 64-col group, 16-row quarter). Wave = K-eighth (128 K/seg).
// B-weights: 32 frags = 128 VGPR/wave (loaded once, reused 512 steps).
// NEW vs round 5:
//  * DEEP-ISSUE K-loop: all 16 A-loads issued before the first wait (8 KB2
//    buffers, 64 VGPR), counted waits 14->0. One full-latency stall per step
//    instead of eight -- the K-loop becomes throughput-bound.
//  * Single-wave flat poll: only wave 0 polls (3 flags/lane), 3x less poll
//    traffic at the coherence point; __syncthreads releases the rest.
// ---------------------------------------------------------------------------
__global__ __launch_bounds__(512, 2) void rnn_persist(
        const _Float16* __restrict__ X16,
        const _Float16* __restrict__ Bpack,
        _Float16* __restrict__ h_hi,   // [2][3][B][H]
        _Float16* __restrict__ h_lo,
        unsigned* __restrict__ flags,  // [192] monotonic step counters
        unsigned* __restrict__ epoch,  // unused (kept for signature)
        const float* __restrict__ b_h,
        const float* __restrict__ b_layers,
        float* __restrict__ out) {
    (void)epoch;

    const int wgid  = blockIdx.x;          // 0..191
    const int layer = wgid >> 6;
    const int cg    = (wgid >> 2) & 15;    // col group 0..15 (64 cols)
    const int rq    = wgid & 3;            // row quarter (16 rows)
    const int n0    = cg * 64;
    const int m0    = rq * 16;

    const int tid   = threadIdx.x;
    const int keid  = tid >> 6;            // wave = K-eighth 0..7
    const int lane  = tid & 63;
    const int rlane = lane & 15;
    const int kq8   = (lane >> 4) * 8;

    __shared__ __align__(16) floatx4 Rbuf[8 * 4 * 64];   // 32 KB: [wave][frag][lane]

    // ---- B weights -> registers (32 frags = 128 VGPR; layer0 uses 20) ----
    half8 b[32];
    {
        const _Float16* Bq = Bpack + (size_t)((wgid >> 2) * 8 + keid) * 16384
                                   + (size_t)lane * 8;
        if (layer == 0) {
            #pragma unroll
            for (int f = 0; f < 20; ++f) LDB(b[f], Bq + f * 512);
        } else {
            #pragma unroll
            for (int f = 0; f < 32; ++f) LDB(b[f], Bq + f * 512);
        }
    }
    // ---- bias: this wave finalizes col sub-block fo = keid>>1 ----
    const int fo    = keid >> 1;           // output frag 0..3 (wave-uniform)
    const int rhalf = keid & 1;            // row pair within frag
    float bvv;
    {
        const float* bp = (layer == 0 ? b_h : b_layers + (size_t)(layer - 1) * HH)
                          + n0 + fo * 16 + rlane;
        LDF(bvv, bp);
    }
    WAITV(0);
    __syncthreads();

    const size_t rowA = (size_t)(m0 + rlane) * HH + (size_t)keid * 128 + kq8;
    const size_t segA = (size_t)layer * BH;                       // h[layer]
    const size_t segB = (size_t)(layer > 0 ? layer - 1 : 0) * BH; // h[layer-1]
    const size_t xoff = (size_t)(m0 + rlane) * II + keid * 32 + kq8;

    const floatx4 zf = (floatx4){0.f, 0.f, 0.f, 0.f};

    for (int t = 0; t < SS; ++t) {
        const int rb = t & 1;
        const _Float16* hi = h_hi + (size_t)rb * 3 * BH;
        const _Float16* lo = h_lo + (size_t)rb * 3 * BH;
        _Float16* nhi = h_hi + (size_t)(rb ^ 1) * 3 * BH;
        _Float16* nlo = h_lo + (size_t)(rb ^ 1) * 3 * BH;
        const _Float16* pAh = hi + segA + rowA;
        const _Float16* pAl = lo + segA + rowA;
        const _Float16* pBh = hi + segB + rowA;
        const _Float16* pBl = lo + segB + rowA;

        floatx4 a0 = zf, a1 = zf, a2 = zf, a3 = zf;
        KB2 K0, K1, K2, K3, K4, K5, K6, K7;

        if (layer == 0) {
            half8 xr;
            const _Float16* pX = X16 + (size_t)t * BB * II + xoff;
            LD16(xr, pX, 0);                                      // 1 out
            ISS2(K0, pAh, pAl, 0);                                // 3
            ISS2(K1, pAh, pAl, 1);                                // 5
            ISS2(K2, pAh, pAl, 2);                                // 7
            ISS2(K3, pAh, pAl, 3);                                // 9 out
            WAITV(8); CMPX2(xr);
            WAITV(6); CMP2(K0,  4);
            WAITV(4); CMP2(K1,  8);
            WAITV(2); CMP2(K2, 12);
            WAITV(0); CMP2(K3, 16);
        } else {
            ISS2(K0, pAh, pAl, 0);
            ISS2(K1, pAh, pAl, 1);
            ISS2(K2, pAh, pAl, 2);
            ISS2(K3, pAh, pAl, 3);
            ISS2(K4, pBh, pBl, 0);
            ISS2(K5, pBh, pBl, 1);
            ISS2(K6, pBh, pBl, 2);
            ISS2(K7, pBh, pBl, 3);                                // 16 out
            WAITV(14); CMP2(K0,  0);
            WAITV(12); CMP2(K1,  4);
            WAITV(10); CMP2(K2,  8);
            WAITV(8);  CMP2(K3, 12);
            WAITV(6);  CMP2(K4, 16);
            WAITV(4);  CMP2(K5, 20);
            WAITV(2);  CMP2(K6, 24);
            WAITV(0);  CMP2(K7, 28);
        }

        // ---- cross-wave K-eighth reduction through LDS ----
        Rbuf[(keid * 4 + 0) * 64 + lane] = a0;
        Rbuf[(keid * 4 + 1) * 64 + lane] = a1;
        Rbuf[(keid * 4 + 2) * 64 + lane] = a2;
        Rbuf[(keid * 4 + 3) * 64 + lane] = a3;
        __syncthreads();

        // ---- wave keid finalizes frag fo=keid>>1, row pair rhalf ----
        {
            floatx4 s = Rbuf[fo * 64 + lane];
            #pragma unroll
            for (int wv = 1; wv < 8; ++wv)
                s += Rbuf[(wv * 4 + fo) * 64 + lane];
            const int n  = n0 + fo * 16 + rlane;
            const int mb = m0 + (lane >> 4) * 4 + rhalf * 2;
            #pragma unroll
            for (int rr = 0; rr < 2; ++rr) {
                const float v = tanhf(s[rhalf * 2 + rr] + bvv);
                const int m = mb + rr;
                const size_t hoff = (size_t)layer * BH + (size_t)m * HH + n;
                const _Float16 vh = (_Float16)v;
                const _Float16 vl = (_Float16)(v - (float)vh);
                ST2C(nhi + hoff, (unsigned)__builtin_bit_cast(unsigned short, vh));
                ST2C(nlo + hoff, (unsigned)__builtin_bit_cast(unsigned short, vl));
                if (layer == 2) out[(size_t)t * BH + (size_t)m * HH + n] = v;
                if (t == SS - 1)
                    out[(size_t)SS * BH + (size_t)layer * BH + (size_t)m * HH + n] = v;
            }
        }

        // ---- drain stores, flat 1-hop barrier, single-wave poll ----
        asm volatile("s_waitcnt vmcnt(0)" ::: "memory");
        __syncthreads();
        if (tid == 0)
            __hip_atomic_store(&flags[wgid], (unsigned)(t + 1),
                               __ATOMIC_RELAXED, __HIP_MEMORY_SCOPE_AGENT);
        if (tid < 64) {
            while (__hip_atomic_load(&flags[tid], __ATOMIC_RELAXED,
                                     __HIP_MEMORY_SCOPE_AGENT) < (unsigned)(t + 1))
                __builtin_amdgcn_s_sleep(1);
            while (__hip_atomic_load(&flags[tid + 64], __ATOMIC_RELAXED,
                                     __HIP_MEMORY_SCOPE_AGENT) < (unsigned)(t + 1))
                __builtin_amdgcn_s_sleep(1);
            while (__hip_atomic_load(&flags[tid + 128], __ATOMIC_RELAXED,
                                     __HIP_MEMORY_SCOPE_AGENT) < (unsigned)(t + 1))
                __builtin_amdgcn_s_sleep(1);
        }
        __syncthreads();
    }
}

// ---------------------------------------------------------------------------
extern "C" void kernel_launch(void* const* d_in, const int* in_sizes, int n_in,
                              void* d_out, int out_size, void* d_ws, size_t ws_size,
                              hipStream_t stream) {
    (void)in_sizes; (void)n_in; (void)out_size; (void)ws_size;
    const float* X   = (const float*)d_in[0];
    const float* Wxh = (const float*)d_in[1];
    const float* Whh = (const float*)d_in[2];
    const float* bh  = (const float*)d_in[3];
    const float* Wl  = (const float*)d_in[4];
    const float* Ul  = (const float*)d_in[5];
    const float* bl  = (const float*)d_in[6];
    float* out = (float*)d_out;

    char* ws = (char*)d_ws;
    _Float16* X16   = (_Float16*)(ws);                                   // 16,777,216 B
    _Float16* Bpack = (_Float16*)(ws + 16777216);                        // 12,582,912 B
    _Float16* h_hi  = (_Float16*)(ws + 16777216 + 12582912);             //    786,432 B
    _Float16* h_lo  = (_Float16*)(ws + 16777216 + 12582912 + 786432);    //    786,432 B
    unsigned* flags = (unsigned*)(ws + 16777216 + 12582912 + 2 * 786432); //    1,024 B

    hipLaunchKernelGGL(prep_misc,  dim3(4096), dim3(256), 0, stream, X, X16, h_hi, h_lo, flags);
    hipLaunchKernelGGL(prep_bpack, dim3(3072), dim3(256), 0, stream, Wxh, Whh, Wl, Ul, Bpack);
    hipLaunchKernelGGL(rnn_persist, dim3(192), dim3(512), 0, stream,
                       X16, Bpack, h_hi, h_lo, flags, flags + 192, bh, bl, out);
}